// Round 3
// baseline (339.116 us; speedup 1.0000x reference)
//
#include <hip/hip_runtime.h>
#include <math.h>

// Problem constants (fixed by the reference)
#define MM 12       // M
#define KK 2        // K
#define DD 512      // D
#define CIN 4096    // C_IN
#define NCLS 8
#define NV 16       // N (videos) == LSTM step count
#define TT 32       // T
// Only LSTM batch row t=31 is ever consumed (rows independent; out uses hs[:, -1, :]).

typedef unsigned long long u64;
typedef __attribute__((ext_vector_type(8))) __bf16 bf16x8;
typedef __attribute__((ext_vector_type(4))) float f32x4;

// ws float offsets
#define PART_F   0            // 4*192*1024 floats
#define POOLED_F 786432       // 16*512
#define TAGA_F   794624       // 256 tags, stride-16 u32 (one 64B line each) = 4096 u32
#define HGLOB_F  799232       // 16*512 self-tagged u64 = 16384 floats (byte off %8==0)
#define PART_KS_STRIDE (192 * 1024)

#define MFMA_BF16(A, B, C) __builtin_amdgcn_mfma_f32_16x16x32_bf16((A), (B), (C), 0, 0, 0)
#define LOADR(p)      __hip_atomic_load((p), __ATOMIC_RELAXED, __HIP_MEMORY_SCOPE_AGENT)
#define LOADACQ(p)    __hip_atomic_load((p), __ATOMIC_ACQUIRE, __HIP_MEMORY_SCOPE_AGENT)
#define STORER(p, v)  __hip_atomic_store((p), (v), __ATOMIC_RELAXED, __HIP_MEMORY_SCOPE_AGENT)
#define STOREREL(p, v) __hip_atomic_store((p), (v), __ATOMIC_RELEASE, __HIP_MEMORY_SCOPE_AGENT)

// ============================================================================
// Kernel 1: GEMM (phase A) + fence + pool (phase B).  256 WGs x 256 threads.
// (unchanged from R2 — serves as the control)
// ============================================================================
__global__ __launch_bounds__(256, 1) void k_gemm_pool(
    const float* __restrict__ base_out, const float* __restrict__ dist,
    const float* __restrict__ w_a,
    float* __restrict__ part, float* __restrict__ pooled,
    unsigned* __restrict__ tagA)
{
  const int wg = blockIdx.x;   // 0..255
  const int tid = threadIdx.x; // 0..255

  __shared__ __align__(16) unsigned short Ah[16 * 40], Al[16 * 40];   // w_a tile hi/lo, pad-40 swizzle
  __shared__ __align__(16) unsigned short Bh[192 * 40], Bl[192 * 40]; // base_sel tile hi/lo
  __shared__ float Asum_s[KK * MM * MM];

  {
    const int ks = wg >> 6, ot = wg & 63;
    const int cc0 = ks * 1024;
    const int wave = tid >> 6, lane = tid & 63;
    const int jf0 = wave * 3;          // this wave's 3 j-fragments

    const int sq = tid & 7;            // cc float4 quad (0..7)
    const int sr = tid >> 3;           // staging row (0..31)
    unsigned boff[6];
#pragma unroll
    for (int rep = 0; rep < 6; ++rep) {
      const int j = sr + 32 * rep;     // 0..191
      const int n = j / 12, m = j - n * 12;
      boff[rep] = (unsigned)(((n * TT + 31) * MM + m) * CIN + cc0 + sq * 4);
    }
    const bool aact = tid < 128;       // A tile: 16 rows x 32cc = 128 float4
    unsigned aoff = aact ? (unsigned)((ot * 16 + (tid >> 3)) * CIN + cc0 + sq * 4) : 0u;

    f32x4 acc0 = {0.f, 0.f, 0.f, 0.f}, acc1 = acc0, acc2 = acc0;

    float4 pa, pb[6];
    if (aact) pa = *(const float4*)&w_a[aoff];
#pragma unroll
    for (int rep = 0; rep < 6; ++rep) pb[rep] = *(const float4*)&base_out[boff[rep]];

    for (int st = 0; st < 32; ++st) {
      __syncthreads();
      if (aact) {
        const int idx = (tid >> 3) * 40 + sq * 4;
        unsigned ux = __float_as_uint(pa.x), uy = __float_as_uint(pa.y);
        unsigned uz = __float_as_uint(pa.z), uw = __float_as_uint(pa.w);
        *(uint2*)&Ah[idx] = make_uint2((ux >> 16) | (uy & 0xFFFF0000u),
                                       (uz >> 16) | (uw & 0xFFFF0000u));
        unsigned lx = __float_as_uint(pa.x - __uint_as_float(ux & 0xFFFF0000u));
        unsigned ly = __float_as_uint(pa.y - __uint_as_float(uy & 0xFFFF0000u));
        unsigned lz = __float_as_uint(pa.z - __uint_as_float(uz & 0xFFFF0000u));
        unsigned lw = __float_as_uint(pa.w - __uint_as_float(uw & 0xFFFF0000u));
        *(uint2*)&Al[idx] = make_uint2((lx >> 16) | (ly & 0xFFFF0000u),
                                       (lz >> 16) | (lw & 0xFFFF0000u));
      }
#pragma unroll
      for (int rep = 0; rep < 6; ++rep) {
        const int idx = (sr + 32 * rep) * 40 + sq * 4;
        unsigned ux = __float_as_uint(pb[rep].x), uy = __float_as_uint(pb[rep].y);
        unsigned uz = __float_as_uint(pb[rep].z), uw = __float_as_uint(pb[rep].w);
        *(uint2*)&Bh[idx] = make_uint2((ux >> 16) | (uy & 0xFFFF0000u),
                                       (uz >> 16) | (uw & 0xFFFF0000u));
        unsigned lx = __float_as_uint(pb[rep].x - __uint_as_float(ux & 0xFFFF0000u));
        unsigned ly = __float_as_uint(pb[rep].y - __uint_as_float(uy & 0xFFFF0000u));
        unsigned lz = __float_as_uint(pb[rep].z - __uint_as_float(uz & 0xFFFF0000u));
        unsigned lw = __float_as_uint(pb[rep].w - __uint_as_float(uw & 0xFFFF0000u));
        *(uint2*)&Bl[idx] = make_uint2((lx >> 16) | (ly & 0xFFFF0000u),
                                       (lz >> 16) | (lw & 0xFFFF0000u));
      }
      __syncthreads();
      if (st < 31) {  // prefetch next 32cc under compute
        aoff += 32;
        if (aact) pa = *(const float4*)&w_a[aoff];
#pragma unroll
        for (int rep = 0; rep < 6; ++rep) {
          boff[rep] += 32;
          pb[rep] = *(const float4*)&base_out[boff[rep]];
        }
      }
      const int koff = (lane >> 4) * 8;
      const int fra = (lane & 15) * 40 + koff;
      bf16x8 oh = *(const bf16x8*)&Ah[fra];
      bf16x8 ol = *(const bf16x8*)&Al[fra];
      {
        const int r0 = ((jf0 + 0) * 16 + (lane & 15)) * 40 + koff;
        bf16x8 jh = *(const bf16x8*)&Bh[r0], jl = *(const bf16x8*)&Bl[r0];
        acc0 = MFMA_BF16(jh, oh, acc0);
        acc0 = MFMA_BF16(jh, ol, acc0);
        acc0 = MFMA_BF16(jl, oh, acc0);
      }
      {
        const int r1 = ((jf0 + 1) * 16 + (lane & 15)) * 40 + koff;
        bf16x8 jh = *(const bf16x8*)&Bh[r1], jl = *(const bf16x8*)&Bl[r1];
        acc1 = MFMA_BF16(jh, oh, acc1);
        acc1 = MFMA_BF16(jh, ol, acc1);
        acc1 = MFMA_BF16(jl, oh, acc1);
      }
      {
        const int r2 = ((jf0 + 2) * 16 + (lane & 15)) * 40 + koff;
        bf16x8 jh = *(const bf16x8*)&Bh[r2], jl = *(const bf16x8*)&Bl[r2];
        acc2 = MFMA_BF16(jh, oh, acc2);
        acc2 = MFMA_BF16(jh, ol, acc2);
        acc2 = MFMA_BF16(jl, oh, acc2);
      }
    }
    // C/D layout: col(o) = lane&15, row(j) = (lane>>4)*4 + reg   [m89-verified]
    const int o = ot * 16 + (lane & 15);
    const int jr = (lane >> 4) * 4;
#pragma unroll
    for (int r = 0; r < 4; ++r) {
      part[((size_t)ks * 192 + (jf0 + 0) * 16 + jr + r) * 1024 + o] = acc0[r];
      part[((size_t)ks * 192 + (jf0 + 1) * 16 + jr + r) * 1024 + o] = acc1[r];
      part[((size_t)ks * 192 + (jf0 + 2) * 16 + jr + r) * 1024 + o] = acc2[r];
    }
    __syncthreads();   // drains vmcnt -> all part stores in L2 before release
    if (tid == 0) STOREREL(&tagA[wg * 16], 1u);
  }

  // ---- fence: all GEMM tiles visible. Wave-0 sweep ----
  if (tid < 64) {
    bool done;
    do {
      unsigned a0 = LOADR(&tagA[(tid      ) * 16]);
      unsigned a1 = LOADR(&tagA[(tid +  64) * 16]);
      unsigned a2 = LOADR(&tagA[(tid + 128) * 16]);
      unsigned a3 = LOADR(&tagA[(tid + 192) * 16]);
      done = __all(a0 == 1u && a1 == 1u && a2 == 1u && a3 == 1u);
    } while (!done);
  }
  __syncthreads();
  (void)LOADACQ(&tagA[0]);   // orders subsequent plain loads of part

  // Phase B: pool — WG (n = wg>>4, c-block = (wg&15)*32)
  {
    const int n = wg >> 4, cb = (wg & 15) * 32;
    const unsigned dbase = (unsigned)((n * TT + 31) * (3 * KK * MM * MM));
    for (int f = tid; f < KK * MM * MM; f += 256)
      Asum_s[f] = dist[dbase + f] + dist[dbase + KK * MM * MM + f]
                + dist[dbase + 2 * KK * MM * MM + f];
    __syncthreads();
    if (tid < 32) {
      const int c = cb + tid;
      float nd[KK][MM];
#pragma unroll
      for (int k = 0; k < KK; ++k)
#pragma unroll
        for (int v = 0; v < MM; ++v) {
          const size_t off = (size_t)(n * MM + v) * 1024 + k * DD + c;
          nd[k][v] = part[off] + part[off + PART_KS_STRIDE]
                   + part[off + 2 * PART_KS_STRIDE] + part[off + 3 * PART_KS_STRIDE];
        }
      float accm = 0.f;
#pragma unroll
      for (int w = 0; w < MM; ++w) {
        float sw = 0.f;
#pragma unroll
        for (int k = 0; k < KK; ++k)
#pragma unroll
          for (int v = 0; v < MM; ++v) sw += nd[k][v] * Asum_s[(k * MM + v) * MM + w];
        accm += fmaxf(sw, 0.f);
      }
      pooled[n * DD + c] = accm * (1.f / 12.f);
    }
  }
  // pooled visibility to kernel 2 via the stream/kernel boundary.
}

// ============================================================================
// Kernel 2: gx + LSTM + classifier.  32 WGs x 1024 threads.
// WG w owns h-dims [w*16, w*16+16) -> 64 gate rows {g*512 + w*16 + j}.
// Sync: NO separate tag. Readers spin directly on self-tagged hg64 words
// (4-deep same-address sampling); publisher uses a RELEASE store (forces
// L2 write-through so remote readers see it at the coherence point promptly).
// ============================================================================
__global__ __launch_bounds__(1024, 4) void k_lstm(
    const float* __restrict__ pooled,
    const float* __restrict__ w_ih, const float* __restrict__ w_hh,
    const float* __restrict__ b_ih, const float* __restrict__ b_hh,
    const float* __restrict__ w_cls, const float* __restrict__ b_cls,
    u64* __restrict__ hg64, float* __restrict__ out)
{
  const int wg = blockIdx.x;    // 0..31
  const int tid = threadIdx.x;  // 0..1023

  __shared__ __align__(16) float whh_s[64][516];  // 132 KB; reused as h-history in classifier
  __shared__ float gx_s[16][64];                  // [step][local gate row]
  __shared__ __align__(16) float h_s[DD];
  __shared__ float dot_s[64];

  // ---- prologue: whh staging and gx overlap (disjoint resources, one barrier) ----
  // stage whh rows (64 x 512 = 128 KB)
  for (int f = tid; f < 64 * 128; f += 1024) {
    const int rr = f >> 7, c4 = (f & 127) * 4;
    const int grow = (rr >> 4) * DD + wg * 16 + (rr & 15);
    *(float4*)&whh_s[rr][c4] = *(const float4*)&w_hh[(size_t)grow * DD + c4];
  }
  // gx: thread t -> (n = t>>6, local row r = t&63); pooled read is wave-uniform
  // (all 64 lanes same address -> L1 broadcast). Same FP accumulation order.
  {
    const int n = tid >> 6, r = tid & 63;
    const int grow = (r >> 4) * DD + wg * 16 + (r & 15);
    const float4* wr = (const float4*)&w_ih[(size_t)grow * DD];
    const float4* pv = (const float4*)&pooled[(size_t)n * DD];
    float a = 0.f;
#pragma unroll 8
    for (int q = 0; q < DD / 4; ++q) {
      float4 x = wr[q], y = pv[q];
      a += x.x * y.x + x.y * y.y + x.z * y.z + x.w * y.w;
    }
    gx_s[n][r] = a + b_ih[grow] + b_hh[grow];
  }
  __syncthreads();

  // ---- LSTM loop: 16 steps; direct data-spin all-gather ----
  {
    float c_reg = 0.f;
    const int r = tid >> 4;    // local gate row 0..63
    const int lj = tid & 15;   // slice lane

    for (int s = 0; s < NV; ++s) {
      if (s == 0) {
        if (tid < DD) h_s[tid] = 0.f;
      } else {
        if (tid < DD) {
          const u64* p = &hg64[(size_t)(s - 1) * DD + tid];
          u64 v = LOADR(p);
          while ((unsigned)v != (unsigned)s) {
            // 4 back-to-back in-flight samples of the same line: detect
            // granularity ~RTT/4 instead of RTT.
            u64 a0 = LOADR(p);
            u64 a1 = LOADR(p);
            u64 a2 = LOADR(p);
            u64 a3 = LOADR(p);
            if ((unsigned)a0 == (unsigned)s)      v = a0;
            else if ((unsigned)a1 == (unsigned)s) v = a1;
            else if ((unsigned)a2 == (unsigned)s) v = a2;
            else                                  v = a3;
          }
          h_s[tid] = __uint_as_float((unsigned)(v >> 32));
        }
      }
      __syncthreads();

      float p = 0.f;
      const float4* wrow = (const float4*)&whh_s[r][0];
      const float4* hv4 = (const float4*)h_s;
#pragma unroll
      for (int q = 0; q < 8; ++q) {
        float4 wv = wrow[lj + 16 * q];
        float4 hv = hv4[lj + 16 * q];
        p += wv.x * hv.x + wv.y * hv.y + wv.z * hv.z + wv.w * hv.w;
      }
#pragma unroll
      for (int off = 8; off; off >>= 1) p += __shfl_down(p, off, 16);
      if (lj == 0) dot_s[r] = p;
      __syncthreads();

      if (tid < 16) {
        const float pi = gx_s[s][tid]      + dot_s[tid];
        const float pf = gx_s[s][16 + tid] + dot_s[16 + tid];
        const float pg = gx_s[s][32 + tid] + dot_s[32 + tid];
        const float po = gx_s[s][48 + tid] + dot_s[48 + tid];
        const float si = 1.f / (1.f + expf(-pi));
        const float sf = 1.f / (1.f + expf(-pf));
        const float so = 1.f / (1.f + expf(-po));
        c_reg = sf * c_reg + si * tanhf(pg);
        const float hn = so * tanhf(c_reg);
        const u64 pk = ((u64)__float_as_uint(hn) << 32) | (u64)(unsigned)(s + 1);
        STOREREL(&hg64[(size_t)s * DD + wg * 16 + tid], pk);   // release: prompt visibility
      }
      // h_s/dot_s only rewritten after next step's barriers (two barriers away)
    }
  }

  // ---- classifier tail (WG 0): h-history into whh_s scratch (whh dead now) ----
  if (wg == 0) {
    float* scratch = &whh_s[0][0];   // rows stride 516
    if (tid < DD) {
      u64 vv[NV];
#pragma unroll
      for (int n = 0; n < NV; ++n) vv[n] = LOADR(&hg64[(size_t)n * DD + tid]);
#pragma unroll
      for (int n = 0; n < NV; ++n) {
        u64 v = vv[n];
        while ((unsigned)v != (unsigned)(n + 1))
          v = LOADR(&hg64[(size_t)n * DD + tid]);   // rare backstop
        scratch[n * 516 + tid] = __uint_as_float((unsigned)(v >> 32));
      }
    }
    __syncthreads();
    if (tid < NV * NCLS) {
      const int n = tid >> 3, cl = tid & 7;
      const float4* hv = (const float4*)&scratch[n * 516];
      const float4* wv = (const float4*)(w_cls + (size_t)cl * DD);
      float a = b_cls[cl];
#pragma unroll 8
      for (int q = 0; q < DD / 4; ++q) {
        float4 x = hv[q], y = wv[q];
        a += x.x * y.x + x.y * y.y + x.z * y.z + x.w * y.w;
      }
      out[tid] = a;
    }
  }
}

extern "C" void kernel_launch(void* const* d_in, const int* in_sizes, int n_in,
                              void* d_out, int out_size, void* d_ws, size_t ws_size,
                              hipStream_t stream) {
  const float* base_out = (const float*)d_in[0];
  const float* dist     = (const float*)d_in[1];
  const float* w_a      = (const float*)d_in[2];
  const float* w_ih     = (const float*)d_in[3];
  const float* w_hh     = (const float*)d_in[4];
  const float* b_ih     = (const float*)d_in[5];
  const float* b_hh     = (const float*)d_in[6];
  const float* w_cls    = (const float*)d_in[7];
  const float* b_cls    = (const float*)d_in[8];
  float* out = (float*)d_out;

  float* ws = (float*)d_ws;
  float* part   = ws + PART_F;
  float* pooled = ws + POOLED_F;
  unsigned* tagA = (unsigned*)(ws + TAGA_F);
  u64* hg64 = (u64*)(ws + HGLOB_F);

  // Tags/values self-validate against the 0xAA re-poison (poison low word
  // 0xAAAAAAAA never equals a live tag 1..16).
  // Kernel boundary on the stream provides part/pooled visibility to k_lstm.
  k_gemm_pool<<<dim3(256), 256, 0, stream>>>(base_out, dist, w_a, part, pooled, tagA);
  k_lstm<<<dim3(32), 1024, 0, stream>>>(pooled, w_ih, w_hh, b_ih, b_hh,
                                        w_cls, b_cls, hg64, out);
}

// Round 4
// 296.306 us; speedup vs baseline: 1.1445x; 1.1445x over previous
//
#include <hip/hip_runtime.h>
#include <math.h>

// Problem constants (fixed by the reference)
#define MM 12       // M
#define KK 2        // K
#define DD 512      // D
#define CIN 4096    // C_IN
#define NCLS 8
#define NV 16       // N (videos) == LSTM step count
#define TT 32       // T
// Only LSTM batch row t=31 is ever consumed (rows independent; out uses hs[:, -1, :]).

typedef unsigned long long u64;
typedef __attribute__((ext_vector_type(8))) __bf16 bf16x8;
typedef __attribute__((ext_vector_type(4))) float f32x4;

// ws float offsets
#define PART_F   0            // 4*192*1024 floats
#define POOLED_F 786432       // 16*512
#define TAGA_F   794624       // 256 tags, stride-16 u32 (one 64B line each) = 4096 u32
#define TAGD_F   798720       // 32 tags, stride-16 u32 = 512 u32
#define HGLOB_F  799232       // 16*512 self-tagged u64 = 16384 floats (byte off %8==0)
#define PART_KS_STRIDE (192 * 1024)

#define MFMA_BF16(A, B, C) __builtin_amdgcn_mfma_f32_16x16x32_bf16((A), (B), (C), 0, 0, 0)
// AGENT scope (k1 internal fence — proven correct/fast there)
#define LOADR(p)      __hip_atomic_load((p), __ATOMIC_RELAXED, __HIP_MEMORY_SCOPE_AGENT)
#define LOADACQ(p)    __hip_atomic_load((p), __ATOMIC_ACQUIRE, __HIP_MEMORY_SCOPE_AGENT)
#define STOREREL(p, v) __hip_atomic_store((p), (v), __ATOMIC_RELEASE, __HIP_MEMORY_SCOPE_AGENT)
// SYSTEM scope (k2 cross-WG sync — sc0+sc1: bypass L1/L2, coherence point = L3.
// Theory: AGENT-scope relaxed stores linger dirty in the publisher XCD's L2 and
// reader polls are served from stale local copies; visibility then rides on
// eviction timing (~5 µs/step, invariant across R0-R2 sync designs).
#define LOADS(p)      __hip_atomic_load((p), __ATOMIC_RELAXED, __HIP_MEMORY_SCOPE_SYSTEM)
#define STORES(p, v)  __hip_atomic_store((p), (v), __ATOMIC_RELAXED, __HIP_MEMORY_SCOPE_SYSTEM)

// ============================================================================
// Kernel 1: GEMM (phase A) + fence + pool (phase B).  256 WGs x 256 threads.
// (byte-identical to R2/R3 — serves as the control)
// ============================================================================
__global__ __launch_bounds__(256, 1) void k_gemm_pool(
    const float* __restrict__ base_out, const float* __restrict__ dist,
    const float* __restrict__ w_a,
    float* __restrict__ part, float* __restrict__ pooled,
    unsigned* __restrict__ tagA)
{
  const int wg = blockIdx.x;   // 0..255
  const int tid = threadIdx.x; // 0..255

  __shared__ __align__(16) unsigned short Ah[16 * 40], Al[16 * 40];   // w_a tile hi/lo, pad-40 swizzle
  __shared__ __align__(16) unsigned short Bh[192 * 40], Bl[192 * 40]; // base_sel tile hi/lo
  __shared__ float Asum_s[KK * MM * MM];

  {
    const int ks = wg >> 6, ot = wg & 63;
    const int cc0 = ks * 1024;
    const int wave = tid >> 6, lane = tid & 63;
    const int jf0 = wave * 3;          // this wave's 3 j-fragments

    const int sq = tid & 7;            // cc float4 quad (0..7)
    const int sr = tid >> 3;           // staging row (0..31)
    unsigned boff[6];
#pragma unroll
    for (int rep = 0; rep < 6; ++rep) {
      const int j = sr + 32 * rep;     // 0..191
      const int n = j / 12, m = j - n * 12;
      boff[rep] = (unsigned)(((n * TT + 31) * MM + m) * CIN + cc0 + sq * 4);
    }
    const bool aact = tid < 128;       // A tile: 16 rows x 32cc = 128 float4
    unsigned aoff = aact ? (unsigned)((ot * 16 + (tid >> 3)) * CIN + cc0 + sq * 4) : 0u;

    f32x4 acc0 = {0.f, 0.f, 0.f, 0.f}, acc1 = acc0, acc2 = acc0;

    float4 pa, pb[6];
    if (aact) pa = *(const float4*)&w_a[aoff];
#pragma unroll
    for (int rep = 0; rep < 6; ++rep) pb[rep] = *(const float4*)&base_out[boff[rep]];

    for (int st = 0; st < 32; ++st) {
      __syncthreads();
      if (aact) {
        const int idx = (tid >> 3) * 40 + sq * 4;
        unsigned ux = __float_as_uint(pa.x), uy = __float_as_uint(pa.y);
        unsigned uz = __float_as_uint(pa.z), uw = __float_as_uint(pa.w);
        *(uint2*)&Ah[idx] = make_uint2((ux >> 16) | (uy & 0xFFFF0000u),
                                       (uz >> 16) | (uw & 0xFFFF0000u));
        unsigned lx = __float_as_uint(pa.x - __uint_as_float(ux & 0xFFFF0000u));
        unsigned ly = __float_as_uint(pa.y - __uint_as_float(uy & 0xFFFF0000u));
        unsigned lz = __float_as_uint(pa.z - __uint_as_float(uz & 0xFFFF0000u));
        unsigned lw = __float_as_uint(pa.w - __uint_as_float(uw & 0xFFFF0000u));
        *(uint2*)&Al[idx] = make_uint2((lx >> 16) | (ly & 0xFFFF0000u),
                                       (lz >> 16) | (lw & 0xFFFF0000u));
      }
#pragma unroll
      for (int rep = 0; rep < 6; ++rep) {
        const int idx = (sr + 32 * rep) * 40 + sq * 4;
        unsigned ux = __float_as_uint(pb[rep].x), uy = __float_as_uint(pb[rep].y);
        unsigned uz = __float_as_uint(pb[rep].z), uw = __float_as_uint(pb[rep].w);
        *(uint2*)&Bh[idx] = make_uint2((ux >> 16) | (uy & 0xFFFF0000u),
                                       (uz >> 16) | (uw & 0xFFFF0000u));
        unsigned lx = __float_as_uint(pb[rep].x - __uint_as_float(ux & 0xFFFF0000u));
        unsigned ly = __float_as_uint(pb[rep].y - __uint_as_float(uy & 0xFFFF0000u));
        unsigned lz = __float_as_uint(pb[rep].z - __uint_as_float(uz & 0xFFFF0000u));
        unsigned lw = __float_as_uint(pb[rep].w - __uint_as_float(uw & 0xFFFF0000u));
        *(uint2*)&Bl[idx] = make_uint2((lx >> 16) | (ly & 0xFFFF0000u),
                                       (lz >> 16) | (lw & 0xFFFF0000u));
      }
      __syncthreads();
      if (st < 31) {  // prefetch next 32cc under compute
        aoff += 32;
        if (aact) pa = *(const float4*)&w_a[aoff];
#pragma unroll
        for (int rep = 0; rep < 6; ++rep) {
          boff[rep] += 32;
          pb[rep] = *(const float4*)&base_out[boff[rep]];
        }
      }
      const int koff = (lane >> 4) * 8;
      const int fra = (lane & 15) * 40 + koff;
      bf16x8 oh = *(const bf16x8*)&Ah[fra];
      bf16x8 ol = *(const bf16x8*)&Al[fra];
      {
        const int r0 = ((jf0 + 0) * 16 + (lane & 15)) * 40 + koff;
        bf16x8 jh = *(const bf16x8*)&Bh[r0], jl = *(const bf16x8*)&Bl[r0];
        acc0 = MFMA_BF16(jh, oh, acc0);
        acc0 = MFMA_BF16(jh, ol, acc0);
        acc0 = MFMA_BF16(jl, oh, acc0);
      }
      {
        const int r1 = ((jf0 + 1) * 16 + (lane & 15)) * 40 + koff;
        bf16x8 jh = *(const bf16x8*)&Bh[r1], jl = *(const bf16x8*)&Bl[r1];
        acc1 = MFMA_BF16(jh, oh, acc1);
        acc1 = MFMA_BF16(jh, ol, acc1);
        acc1 = MFMA_BF16(jl, oh, acc1);
      }
      {
        const int r2 = ((jf0 + 2) * 16 + (lane & 15)) * 40 + koff;
        bf16x8 jh = *(const bf16x8*)&Bh[r2], jl = *(const bf16x8*)&Bl[r2];
        acc2 = MFMA_BF16(jh, oh, acc2);
        acc2 = MFMA_BF16(jh, ol, acc2);
        acc2 = MFMA_BF16(jl, oh, acc2);
      }
    }
    // C/D layout: col(o) = lane&15, row(j) = (lane>>4)*4 + reg   [m89-verified]
    const int o = ot * 16 + (lane & 15);
    const int jr = (lane >> 4) * 4;
#pragma unroll
    for (int r = 0; r < 4; ++r) {
      part[((size_t)ks * 192 + (jf0 + 0) * 16 + jr + r) * 1024 + o] = acc0[r];
      part[((size_t)ks * 192 + (jf0 + 1) * 16 + jr + r) * 1024 + o] = acc1[r];
      part[((size_t)ks * 192 + (jf0 + 2) * 16 + jr + r) * 1024 + o] = acc2[r];
    }
    __syncthreads();   // drains vmcnt -> all part stores in L2 before release
    if (tid == 0) STOREREL(&tagA[wg * 16], 1u);
  }

  // ---- fence: all GEMM tiles visible. Wave-0 sweep ----
  if (tid < 64) {
    bool done;
    do {
      unsigned a0 = LOADR(&tagA[(tid      ) * 16]);
      unsigned a1 = LOADR(&tagA[(tid +  64) * 16]);
      unsigned a2 = LOADR(&tagA[(tid + 128) * 16]);
      unsigned a3 = LOADR(&tagA[(tid + 192) * 16]);
      done = __all(a0 == 1u && a1 == 1u && a2 == 1u && a3 == 1u);
    } while (!done);
  }
  __syncthreads();
  (void)LOADACQ(&tagA[0]);   // orders subsequent plain loads of part

  // Phase B: pool — WG (n = wg>>4, c-block = (wg&15)*32)
  {
    const int n = wg >> 4, cb = (wg & 15) * 32;
    const unsigned dbase = (unsigned)((n * TT + 31) * (3 * KK * MM * MM));
    for (int f = tid; f < KK * MM * MM; f += 256)
      Asum_s[f] = dist[dbase + f] + dist[dbase + KK * MM * MM + f]
                + dist[dbase + 2 * KK * MM * MM + f];
    __syncthreads();
    if (tid < 32) {
      const int c = cb + tid;
      float nd[KK][MM];
#pragma unroll
      for (int k = 0; k < KK; ++k)
#pragma unroll
        for (int v = 0; v < MM; ++v) {
          const size_t off = (size_t)(n * MM + v) * 1024 + k * DD + c;
          nd[k][v] = part[off] + part[off + PART_KS_STRIDE]
                   + part[off + 2 * PART_KS_STRIDE] + part[off + 3 * PART_KS_STRIDE];
        }
      float accm = 0.f;
#pragma unroll
      for (int w = 0; w < MM; ++w) {
        float sw = 0.f;
#pragma unroll
        for (int k = 0; k < KK; ++k)
#pragma unroll
          for (int v = 0; v < MM; ++v) sw += nd[k][v] * Asum_s[(k * MM + v) * MM + w];
        accm += fmaxf(sw, 0.f);
      }
      pooled[n * DD + c] = accm * (1.f / 12.f);
    }
  }
  // pooled visibility to kernel 2 via the stream/kernel boundary.
}

// ============================================================================
// Kernel 2: gx + LSTM + classifier.  32 WGs x 1024 threads.
// EXACT R2 structure (93 µs best). Single variable vs R2: all cross-WG sync
// (tagD + hg64) uses SYSTEM scope -> sc0 sc1 -> L1/L2 bypass, L3 coherence.
// ============================================================================
__global__ __launch_bounds__(1024, 4) void k_lstm(
    const float* __restrict__ pooled,
    const float* __restrict__ w_ih, const float* __restrict__ w_hh,
    const float* __restrict__ b_ih, const float* __restrict__ b_hh,
    const float* __restrict__ w_cls, const float* __restrict__ b_cls,
    unsigned* __restrict__ tagD, u64* __restrict__ hg64,
    float* __restrict__ out)
{
  const int wg = blockIdx.x;    // 0..31
  const int tid = threadIdx.x;  // 0..1023

  __shared__ __align__(16) float whh_s[64][516];  // 132 KB; also scratch for pooled / h-history
  __shared__ float gx_s[16][64];                  // [step][local gate row]
  __shared__ __align__(16) float h_s[DD];
  __shared__ float dot_s[64];

  float* scratch = &whh_s[0][0];  // rows 0..15, stride 516 (16B-aligned rows)

  // ---- stage pooled (16x512) into scratch ----
  for (int f = tid; f < NV * DD; f += 1024)
    scratch[(f >> 9) * 516 + (f & 511)] = pooled[f];
  __syncthreads();

  // ---- gx: thread t -> (n = t&15, local row r = t>>4); same FP order as before ----
  {
    const int n = tid & 15, r = tid >> 4;
    const int grow = (r >> 4) * DD + wg * 16 + (r & 15);
    const float4* wr = (const float4*)&w_ih[(size_t)grow * DD];
    const float4* pv = (const float4*)&scratch[n * 516];
    float a = 0.f;
#pragma unroll 8
    for (int q = 0; q < DD / 4; ++q) {
      float4 x = wr[q], y = pv[q];
      a += x.x * y.x + x.y * y.y + x.z * y.z + x.w * y.w;
    }
    gx_s[n][r] = a + b_ih[grow] + b_hh[grow];
  }
  __syncthreads();   // all scratch reads done before whh overwrites it

  // ---- stage whh rows (64 x 512 = 128 KB) ----
  for (int f = tid; f < 64 * 128; f += 1024) {
    const int rr = f >> 7, c4 = (f & 127) * 4;
    const int grow = (rr >> 4) * DD + wg * 16 + (rr & 15);
    *(float4*)&whh_s[rr][c4] = *(const float4*)&w_hh[(size_t)grow * DD + c4];
  }
  __syncthreads();

  // ---- LSTM loop: 16 steps, 32-WG all-gather per step ----
  {
    float c_reg = 0.f;
    const int r = tid >> 4;    // local gate row 0..63
    const int lj = tid & 15;   // slice lane

    for (int s = 0; s < NV; ++s) {
      if (s == 0) {
        if (tid < DD) h_s[tid] = 0.f;
      } else {
        if (tid < 64) {
          bool done;
          do {
            int t0 = (int)LOADS(&tagD[(tid & 31) * 16]);
            done = __all(t0 >= s);     // signed: 0xAA poison is negative
          } while (!done);
        }
        __syncthreads();
        if (tid < DD) {
          u64 v = LOADS(&hg64[(size_t)(s - 1) * DD + tid]);
          while ((unsigned)v != (unsigned)s)
            v = LOADS(&hg64[(size_t)(s - 1) * DD + tid]);   // backstop
          h_s[tid] = __uint_as_float((unsigned)(v >> 32));
        }
      }
      __syncthreads();

      float p = 0.f;
      const float4* wrow = (const float4*)&whh_s[r][0];
      const float4* hv4 = (const float4*)h_s;
#pragma unroll
      for (int q = 0; q < 8; ++q) {
        float4 wv = wrow[lj + 16 * q];
        float4 hv = hv4[lj + 16 * q];
        p += wv.x * hv.x + wv.y * hv.y + wv.z * hv.z + wv.w * hv.w;
      }
#pragma unroll
      for (int off = 8; off; off >>= 1) p += __shfl_down(p, off, 16);
      if (lj == 0) dot_s[r] = p;
      __syncthreads();

      if (tid < 16) {
        const float pi = gx_s[s][tid]      + dot_s[tid];
        const float pf = gx_s[s][16 + tid] + dot_s[16 + tid];
        const float pg = gx_s[s][32 + tid] + dot_s[32 + tid];
        const float po = gx_s[s][48 + tid] + dot_s[48 + tid];
        const float si = 1.f / (1.f + expf(-pi));
        const float sf = 1.f / (1.f + expf(-pf));
        const float so = 1.f / (1.f + expf(-po));
        c_reg = sf * c_reg + si * tanhf(pg);
        const float hn = so * tanhf(c_reg);
        const u64 pk = ((u64)__float_as_uint(hn) << 32) | (u64)(unsigned)(s + 1);
        STORES(&hg64[(size_t)s * DD + wg * 16 + tid], pk);
      }
      if (tid == 0) STORES(&tagD[wg * 16], (unsigned)(s + 1));
      // h_s/dot_s only rewritten after next step's barriers (two barriers away)
    }
  }

  // ---- classifier tail (WG 0) ----
  if (wg == 0) {
    if (tid < 64) {
      bool done;
      do {
        int t0 = (int)LOADS(&tagD[(tid & 31) * 16]);
        done = __all(t0 >= NV);
      } while (!done);
    }
    __syncthreads();
    if (tid < DD) {
      u64 vv[NV];
#pragma unroll
      for (int n = 0; n < NV; ++n) vv[n] = LOADS(&hg64[(size_t)n * DD + tid]);
#pragma unroll
      for (int n = 0; n < NV; ++n) {
        u64 v = vv[n];
        while ((unsigned)v != (unsigned)(n + 1))
          v = LOADS(&hg64[(size_t)n * DD + tid]);   // backstop
        scratch[n * 516 + tid] = __uint_as_float((unsigned)(v >> 32));
      }
    }
    __syncthreads();
    if (tid < NV * NCLS) {
      const int n = tid >> 3, cl = tid & 7;
      const float4* hv = (const float4*)&scratch[n * 516];
      const float4* wv = (const float4*)(w_cls + (size_t)cl * DD);
      float a = b_cls[cl];
#pragma unroll 8
      for (int q = 0; q < DD / 4; ++q) {
        float4 x = hv[q], y = wv[q];
        a += x.x * y.x + x.y * y.y + x.z * y.z + x.w * y.w;
      }
      out[tid] = a;
    }
  }
}

extern "C" void kernel_launch(void* const* d_in, const int* in_sizes, int n_in,
                              void* d_out, int out_size, void* d_ws, size_t ws_size,
                              hipStream_t stream) {
  const float* base_out = (const float*)d_in[0];
  const float* dist     = (const float*)d_in[1];
  const float* w_a      = (const float*)d_in[2];
  const float* w_ih     = (const float*)d_in[3];
  const float* w_hh     = (const float*)d_in[4];
  const float* b_ih     = (const float*)d_in[5];
  const float* b_hh     = (const float*)d_in[6];
  const float* w_cls    = (const float*)d_in[7];
  const float* b_cls    = (const float*)d_in[8];
  float* out = (float*)d_out;

  float* ws = (float*)d_ws;
  float* part   = ws + PART_F;
  float* pooled = ws + POOLED_F;
  unsigned* tagA = (unsigned*)(ws + TAGA_F);
  unsigned* tagD = (unsigned*)(ws + TAGD_F);
  u64* hg64 = (u64*)(ws + HGLOB_F);

  // Tags/values self-validate against the 0xAA re-poison (poison low word
  // 0xAAAAAAAA never equals a live tag 1..16; as signed int it is negative).
  // Kernel boundary on the stream provides part/pooled visibility to k_lstm.
  k_gemm_pool<<<dim3(256), 256, 0, stream>>>(base_out, dist, w_a, part, pooled, tagA);
  k_lstm<<<dim3(32), 1024, 0, stream>>>(pooled, w_ih, w_hh, b_ih, b_hh,
                                        w_cls, b_cls, tagD, hg64, out);
}

// Round 5
// 295.288 us; speedup vs baseline: 1.1484x; 1.0034x over previous
//
#include <hip/hip_runtime.h>
#include <math.h>

// Problem constants (fixed by the reference)
#define MM 12       // M
#define KK 2        // K
#define DD 512      // D
#define CIN 4096    // C_IN
#define NCLS 8
#define NV 16       // N (videos) == LSTM step count
#define TT 32       // T
// Only LSTM batch row t=31 is ever consumed (rows independent; out uses hs[:, -1, :]).

typedef unsigned long long u64;
typedef __attribute__((ext_vector_type(8))) __bf16 bf16x8;
typedef __attribute__((ext_vector_type(4))) float f32x4;

// ws float offsets
#define PART_F   0            // 4*192*1024 floats
#define POOLED_F 786432       // 16*512
#define TAGA_F   794624       // 256 tags, stride-16 u32 (one 64B line each) = 4096 u32
#define TAGD_F   798720       // 32 tags, stride-16 u32 = 512 u32
#define HGLOB_F  799232       // 16*512 self-tagged u64 = 16384 floats (byte off %8==0)
#define PART_KS_STRIDE (192 * 1024)

#define MFMA_BF16(A, B, C) __builtin_amdgcn_mfma_f32_16x16x32_bf16((A), (B), (C), 0, 0, 0)
// AGENT scope (k1 internal fence — proven correct/fast there)
#define LOADR(p)      __hip_atomic_load((p), __ATOMIC_RELAXED, __HIP_MEMORY_SCOPE_AGENT)
#define LOADACQ(p)    __hip_atomic_load((p), __ATOMIC_ACQUIRE, __HIP_MEMORY_SCOPE_AGENT)
#define STOREREL(p, v) __hip_atomic_store((p), (v), __ATOMIC_RELEASE, __HIP_MEMORY_SCOPE_AGENT)
// SYSTEM scope reads (k2 cross-WG sync — proven ≡ agent in R4, kept from R4 base)
#define LOADS(p)      __hip_atomic_load((p), __ATOMIC_RELAXED, __HIP_MEMORY_SCOPE_SYSTEM)
// R5 single variable: publishes are atomic RMW (exchange) instead of plain
// relaxed stores. Theory: fire-and-forget stores linger in write-coalescing
// buffers (nothing ever drains vmcnt behind them in the loop) -> multi-µs
// visibility, invariant to reader structure/scope/parties (R0-R4 data).
// Atomics execute AT the coherence point: a swap is a push, not a lazy WB.
#define EXCHS(p, v)   (void)__hip_atomic_exchange((p), (v), __ATOMIC_RELAXED, __HIP_MEMORY_SCOPE_SYSTEM)

// ============================================================================
// Kernel 1: GEMM (phase A) + fence + pool (phase B).  256 WGs x 256 threads.
// (byte-identical to R2/R3/R4 — serves as the control)
// ============================================================================
__global__ __launch_bounds__(256, 1) void k_gemm_pool(
    const float* __restrict__ base_out, const float* __restrict__ dist,
    const float* __restrict__ w_a,
    float* __restrict__ part, float* __restrict__ pooled,
    unsigned* __restrict__ tagA)
{
  const int wg = blockIdx.x;   // 0..255
  const int tid = threadIdx.x; // 0..255

  __shared__ __align__(16) unsigned short Ah[16 * 40], Al[16 * 40];   // w_a tile hi/lo, pad-40 swizzle
  __shared__ __align__(16) unsigned short Bh[192 * 40], Bl[192 * 40]; // base_sel tile hi/lo
  __shared__ float Asum_s[KK * MM * MM];

  {
    const int ks = wg >> 6, ot = wg & 63;
    const int cc0 = ks * 1024;
    const int wave = tid >> 6, lane = tid & 63;
    const int jf0 = wave * 3;          // this wave's 3 j-fragments

    const int sq = tid & 7;            // cc float4 quad (0..7)
    const int sr = tid >> 3;           // staging row (0..31)
    unsigned boff[6];
#pragma unroll
    for (int rep = 0; rep < 6; ++rep) {
      const int j = sr + 32 * rep;     // 0..191
      const int n = j / 12, m = j - n * 12;
      boff[rep] = (unsigned)(((n * TT + 31) * MM + m) * CIN + cc0 + sq * 4);
    }
    const bool aact = tid < 128;       // A tile: 16 rows x 32cc = 128 float4
    unsigned aoff = aact ? (unsigned)((ot * 16 + (tid >> 3)) * CIN + cc0 + sq * 4) : 0u;

    f32x4 acc0 = {0.f, 0.f, 0.f, 0.f}, acc1 = acc0, acc2 = acc0;

    float4 pa, pb[6];
    if (aact) pa = *(const float4*)&w_a[aoff];
#pragma unroll
    for (int rep = 0; rep < 6; ++rep) pb[rep] = *(const float4*)&base_out[boff[rep]];

    for (int st = 0; st < 32; ++st) {
      __syncthreads();
      if (aact) {
        const int idx = (tid >> 3) * 40 + sq * 4;
        unsigned ux = __float_as_uint(pa.x), uy = __float_as_uint(pa.y);
        unsigned uz = __float_as_uint(pa.z), uw = __float_as_uint(pa.w);
        *(uint2*)&Ah[idx] = make_uint2((ux >> 16) | (uy & 0xFFFF0000u),
                                       (uz >> 16) | (uw & 0xFFFF0000u));
        unsigned lx = __float_as_uint(pa.x - __uint_as_float(ux & 0xFFFF0000u));
        unsigned ly = __float_as_uint(pa.y - __uint_as_float(uy & 0xFFFF0000u));
        unsigned lz = __float_as_uint(pa.z - __uint_as_float(uz & 0xFFFF0000u));
        unsigned lw = __float_as_uint(pa.w - __uint_as_float(uw & 0xFFFF0000u));
        *(uint2*)&Al[idx] = make_uint2((lx >> 16) | (ly & 0xFFFF0000u),
                                       (lz >> 16) | (lw & 0xFFFF0000u));
      }
#pragma unroll
      for (int rep = 0; rep < 6; ++rep) {
        const int idx = (sr + 32 * rep) * 40 + sq * 4;
        unsigned ux = __float_as_uint(pb[rep].x), uy = __float_as_uint(pb[rep].y);
        unsigned uz = __float_as_uint(pb[rep].z), uw = __float_as_uint(pb[rep].w);
        *(uint2*)&Bh[idx] = make_uint2((ux >> 16) | (uy & 0xFFFF0000u),
                                       (uz >> 16) | (uw & 0xFFFF0000u));
        unsigned lx = __float_as_uint(pb[rep].x - __uint_as_float(ux & 0xFFFF0000u));
        unsigned ly = __float_as_uint(pb[rep].y - __uint_as_float(uy & 0xFFFF0000u));
        unsigned lz = __float_as_uint(pb[rep].z - __uint_as_float(uz & 0xFFFF0000u));
        unsigned lw = __float_as_uint(pb[rep].w - __uint_as_float(uw & 0xFFFF0000u));
        *(uint2*)&Bl[idx] = make_uint2((lx >> 16) | (ly & 0xFFFF0000u),
                                       (lz >> 16) | (lw & 0xFFFF0000u));
      }
      __syncthreads();
      if (st < 31) {  // prefetch next 32cc under compute
        aoff += 32;
        if (aact) pa = *(const float4*)&w_a[aoff];
#pragma unroll
        for (int rep = 0; rep < 6; ++rep) {
          boff[rep] += 32;
          pb[rep] = *(const float4*)&base_out[boff[rep]];
        }
      }
      const int koff = (lane >> 4) * 8;
      const int fra = (lane & 15) * 40 + koff;
      bf16x8 oh = *(const bf16x8*)&Ah[fra];
      bf16x8 ol = *(const bf16x8*)&Al[fra];
      {
        const int r0 = ((jf0 + 0) * 16 + (lane & 15)) * 40 + koff;
        bf16x8 jh = *(const bf16x8*)&Bh[r0], jl = *(const bf16x8*)&Bl[r0];
        acc0 = MFMA_BF16(jh, oh, acc0);
        acc0 = MFMA_BF16(jh, ol, acc0);
        acc0 = MFMA_BF16(jl, oh, acc0);
      }
      {
        const int r1 = ((jf0 + 1) * 16 + (lane & 15)) * 40 + koff;
        bf16x8 jh = *(const bf16x8*)&Bh[r1], jl = *(const bf16x8*)&Bl[r1];
        acc1 = MFMA_BF16(jh, oh, acc1);
        acc1 = MFMA_BF16(jh, ol, acc1);
        acc1 = MFMA_BF16(jl, oh, acc1);
      }
      {
        const int r2 = ((jf0 + 2) * 16 + (lane & 15)) * 40 + koff;
        bf16x8 jh = *(const bf16x8*)&Bh[r2], jl = *(const bf16x8*)&Bl[r2];
        acc2 = MFMA_BF16(jh, oh, acc2);
        acc2 = MFMA_BF16(jh, ol, acc2);
        acc2 = MFMA_BF16(jl, oh, acc2);
      }
    }
    // C/D layout: col(o) = lane&15, row(j) = (lane>>4)*4 + reg   [m89-verified]
    const int o = ot * 16 + (lane & 15);
    const int jr = (lane >> 4) * 4;
#pragma unroll
    for (int r = 0; r < 4; ++r) {
      part[((size_t)ks * 192 + (jf0 + 0) * 16 + jr + r) * 1024 + o] = acc0[r];
      part[((size_t)ks * 192 + (jf0 + 1) * 16 + jr + r) * 1024 + o] = acc1[r];
      part[((size_t)ks * 192 + (jf0 + 2) * 16 + jr + r) * 1024 + o] = acc2[r];
    }
    __syncthreads();   // drains vmcnt -> all part stores in L2 before release
    if (tid == 0) STOREREL(&tagA[wg * 16], 1u);
  }

  // ---- fence: all GEMM tiles visible. Wave-0 sweep ----
  if (tid < 64) {
    bool done;
    do {
      unsigned a0 = LOADR(&tagA[(tid      ) * 16]);
      unsigned a1 = LOADR(&tagA[(tid +  64) * 16]);
      unsigned a2 = LOADR(&tagA[(tid + 128) * 16]);
      unsigned a3 = LOADR(&tagA[(tid + 192) * 16]);
      done = __all(a0 == 1u && a1 == 1u && a2 == 1u && a3 == 1u);
    } while (!done);
  }
  __syncthreads();
  (void)LOADACQ(&tagA[0]);   // orders subsequent plain loads of part

  // Phase B: pool — WG (n = wg>>4, c-block = (wg&15)*32)
  {
    const int n = wg >> 4, cb = (wg & 15) * 32;
    const unsigned dbase = (unsigned)((n * TT + 31) * (3 * KK * MM * MM));
    for (int f = tid; f < KK * MM * MM; f += 256)
      Asum_s[f] = dist[dbase + f] + dist[dbase + KK * MM * MM + f]
                + dist[dbase + 2 * KK * MM * MM + f];
    __syncthreads();
    if (tid < 32) {
      const int c = cb + tid;
      float nd[KK][MM];
#pragma unroll
      for (int k = 0; k < KK; ++k)
#pragma unroll
        for (int v = 0; v < MM; ++v) {
          const size_t off = (size_t)(n * MM + v) * 1024 + k * DD + c;
          nd[k][v] = part[off] + part[off + PART_KS_STRIDE]
                   + part[off + 2 * PART_KS_STRIDE] + part[off + 3 * PART_KS_STRIDE];
        }
      float accm = 0.f;
#pragma unroll
      for (int w = 0; w < MM; ++w) {
        float sw = 0.f;
#pragma unroll
        for (int k = 0; k < KK; ++k)
#pragma unroll
          for (int v = 0; v < MM; ++v) sw += nd[k][v] * Asum_s[(k * MM + v) * MM + w];
        accm += fmaxf(sw, 0.f);
      }
      pooled[n * DD + c] = accm * (1.f / 12.f);
    }
  }
  // pooled visibility to kernel 2 via the stream/kernel boundary.
}

// ============================================================================
// Kernel 2: gx + LSTM + classifier.  32 WGs x 1024 threads.
// EXACT R2/R4 structure (93 µs best). Single variable vs R4: publishes
// (hg64 values + tagD) are atomic exchanges instead of relaxed stores.
// ============================================================================
__global__ __launch_bounds__(1024, 4) void k_lstm(
    const float* __restrict__ pooled,
    const float* __restrict__ w_ih, const float* __restrict__ w_hh,
    const float* __restrict__ b_ih, const float* __restrict__ b_hh,
    const float* __restrict__ w_cls, const float* __restrict__ b_cls,
    unsigned* __restrict__ tagD, u64* __restrict__ hg64,
    float* __restrict__ out)
{
  const int wg = blockIdx.x;    // 0..31
  const int tid = threadIdx.x;  // 0..1023

  __shared__ __align__(16) float whh_s[64][516];  // 132 KB; also scratch for pooled / h-history
  __shared__ float gx_s[16][64];                  // [step][local gate row]
  __shared__ __align__(16) float h_s[DD];
  __shared__ float dot_s[64];

  float* scratch = &whh_s[0][0];  // rows 0..15, stride 516 (16B-aligned rows)

  // ---- stage pooled (16x512) into scratch ----
  for (int f = tid; f < NV * DD; f += 1024)
    scratch[(f >> 9) * 516 + (f & 511)] = pooled[f];
  __syncthreads();

  // ---- gx: thread t -> (n = t&15, local row r = t>>4); same FP order as before ----
  {
    const int n = tid & 15, r = tid >> 4;
    const int grow = (r >> 4) * DD + wg * 16 + (r & 15);
    const float4* wr = (const float4*)&w_ih[(size_t)grow * DD];
    const float4* pv = (const float4*)&scratch[n * 516];
    float a = 0.f;
#pragma unroll 8
    for (int q = 0; q < DD / 4; ++q) {
      float4 x = wr[q], y = pv[q];
      a += x.x * y.x + x.y * y.y + x.z * y.z + x.w * y.w;
    }
    gx_s[n][r] = a + b_ih[grow] + b_hh[grow];
  }
  __syncthreads();   // all scratch reads done before whh overwrites it

  // ---- stage whh rows (64 x 512 = 128 KB) ----
  for (int f = tid; f < 64 * 128; f += 1024) {
    const int rr = f >> 7, c4 = (f & 127) * 4;
    const int grow = (rr >> 4) * DD + wg * 16 + (rr & 15);
    *(float4*)&whh_s[rr][c4] = *(const float4*)&w_hh[(size_t)grow * DD + c4];
  }
  __syncthreads();

  // ---- LSTM loop: 16 steps, 32-WG all-gather per step ----
  {
    float c_reg = 0.f;
    const int r = tid >> 4;    // local gate row 0..63
    const int lj = tid & 15;   // slice lane

    for (int s = 0; s < NV; ++s) {
      if (s == 0) {
        if (tid < DD) h_s[tid] = 0.f;
      } else {
        if (tid < 64) {
          bool done;
          do {
            int t0 = (int)LOADS(&tagD[(tid & 31) * 16]);
            done = __all(t0 >= s);     // signed: 0xAA poison is negative
          } while (!done);
        }
        __syncthreads();
        if (tid < DD) {
          u64 v = LOADS(&hg64[(size_t)(s - 1) * DD + tid]);
          while ((unsigned)v != (unsigned)s)
            v = LOADS(&hg64[(size_t)(s - 1) * DD + tid]);   // backstop
          h_s[tid] = __uint_as_float((unsigned)(v >> 32));
        }
      }
      __syncthreads();

      float p = 0.f;
      const float4* wrow = (const float4*)&whh_s[r][0];
      const float4* hv4 = (const float4*)h_s;
#pragma unroll
      for (int q = 0; q < 8; ++q) {
        float4 wv = wrow[lj + 16 * q];
        float4 hv = hv4[lj + 16 * q];
        p += wv.x * hv.x + wv.y * hv.y + wv.z * hv.z + wv.w * hv.w;
      }
#pragma unroll
      for (int off = 8; off; off >>= 1) p += __shfl_down(p, off, 16);
      if (lj == 0) dot_s[r] = p;
      __syncthreads();

      if (tid < 16) {
        const float pi = gx_s[s][tid]      + dot_s[tid];
        const float pf = gx_s[s][16 + tid] + dot_s[16 + tid];
        const float pg = gx_s[s][32 + tid] + dot_s[32 + tid];
        const float po = gx_s[s][48 + tid] + dot_s[48 + tid];
        const float si = 1.f / (1.f + expf(-pi));
        const float sf = 1.f / (1.f + expf(-pf));
        const float so = 1.f / (1.f + expf(-po));
        c_reg = sf * c_reg + si * tanhf(pg);
        const float hn = so * tanhf(c_reg);
        const u64 pk = ((u64)__float_as_uint(hn) << 32) | (u64)(unsigned)(s + 1);
        EXCHS(&hg64[(size_t)s * DD + wg * 16 + tid], pk);   // RMW: executes at coherence point
      }
      if (tid == 0) EXCHS(&tagD[wg * 16], (unsigned)(s + 1));
      // h_s/dot_s only rewritten after next step's barriers (two barriers away)
    }
  }

  // ---- classifier tail (WG 0) ----
  if (wg == 0) {
    if (tid < 64) {
      bool done;
      do {
        int t0 = (int)LOADS(&tagD[(tid & 31) * 16]);
        done = __all(t0 >= NV);
      } while (!done);
    }
    __syncthreads();
    if (tid < DD) {
      u64 vv[NV];
#pragma unroll
      for (int n = 0; n < NV; ++n) vv[n] = LOADS(&hg64[(size_t)n * DD + tid]);
#pragma unroll
      for (int n = 0; n < NV; ++n) {
        u64 v = vv[n];
        while ((unsigned)v != (unsigned)(n + 1))
          v = LOADS(&hg64[(size_t)n * DD + tid]);   // backstop
        scratch[n * 516 + tid] = __uint_as_float((unsigned)(v >> 32));
      }
    }
    __syncthreads();
    if (tid < NV * NCLS) {
      const int n = tid >> 3, cl = tid & 7;
      const float4* hv = (const float4*)&scratch[n * 516];
      const float4* wv = (const float4*)(w_cls + (size_t)cl * DD);
      float a = b_cls[cl];
#pragma unroll 8
      for (int q = 0; q < DD / 4; ++q) {
        float4 x = hv[q], y = wv[q];
        a += x.x * y.x + x.y * y.y + x.z * y.z + x.w * y.w;
      }
      out[tid] = a;
    }
  }
}

extern "C" void kernel_launch(void* const* d_in, const int* in_sizes, int n_in,
                              void* d_out, int out_size, void* d_ws, size_t ws_size,
                              hipStream_t stream) {
  const float* base_out = (const float*)d_in[0];
  const float* dist     = (const float*)d_in[1];
  const float* w_a      = (const float*)d_in[2];
  const float* w_ih     = (const float*)d_in[3];
  const float* w_hh     = (const float*)d_in[4];
  const float* b_ih     = (const float*)d_in[5];
  const float* b_hh     = (const float*)d_in[6];
  const float* w_cls    = (const float*)d_in[7];
  const float* b_cls    = (const float*)d_in[8];
  float* out = (float*)d_out;

  float* ws = (float*)d_ws;
  float* part   = ws + PART_F;
  float* pooled = ws + POOLED_F;
  unsigned* tagA = (unsigned*)(ws + TAGA_F);
  unsigned* tagD = (unsigned*)(ws + TAGD_F);
  u64* hg64 = (u64*)(ws + HGLOB_F);

  // Tags/values self-validate against the 0xAA re-poison (poison low word
  // 0xAAAAAAAA never equals a live tag 1..16; as signed int it is negative).
  // Kernel boundary on the stream provides part/pooled visibility to k_lstm.
  k_gemm_pool<<<dim3(256), 256, 0, stream>>>(base_out, dist, w_a, part, pooled, tagA);
  k_lstm<<<dim3(32), 1024, 0, stream>>>(pooled, w_ih, w_hh, b_ih, b_hh,
                                        w_cls, b_cls, tagD, hg64, out);
}

// Round 6
// 282.837 us; speedup vs baseline: 1.1990x; 1.0440x over previous
//
#include <hip/hip_runtime.h>
#include <math.h>

// Problem constants (fixed by the reference)
#define MM 12       // M
#define KK 2        // K
#define DD 512      // D
#define CIN 4096    // C_IN
#define NCLS 8
#define NV 16       // N (videos) == LSTM step count
#define TT 32       // T
// Only LSTM batch row t=31 is ever consumed (rows independent; out uses hs[:, -1, :]).

typedef unsigned long long u64;
typedef __attribute__((ext_vector_type(8))) __bf16 bf16x8;
typedef __attribute__((ext_vector_type(4))) float f32x4;

// ws float offsets (end 849920 floats = 3.24 MiB <= ws)
#define PART_F   0            // 4*192*1024 floats
#define POOLED_F 786432       // 16*512 -> ends 794624
#define TAGA_F   794624       // 256 tags, stride-16 u32 -> ends 798720
#define TAGGX_F  798720       // 128 tags, stride-16 u32 -> ends 800768
#define HGLOB_F  800768       // 16*512 self-tagged u64 = 16384 floats (8B aligned)
#define GX_F     817152       // 32*16*64 floats = 32768 -> ends 849920
#define PART_KS_STRIDE (192 * 1024)

#define MFMA_BF16(A, B, C) __builtin_amdgcn_mfma_f32_16x16x32_bf16((A), (B), (C), 0, 0, 0)
// AGENT scope ops (k1 + gx handoff): release/acquire do L2 writeback/invalidate
// on gfx950 -> the ONLY proven cross-XCD bulk-data handoff in this kernel family.
#define LOADR(p)      __hip_atomic_load((p), __ATOMIC_RELAXED, __HIP_MEMORY_SCOPE_AGENT)
#define LOADACQ(p)    __hip_atomic_load((p), __ATOMIC_ACQUIRE, __HIP_MEMORY_SCOPE_AGENT)
#define STOREREL(p, v) __hip_atomic_store((p), (v), __ATOMIC_RELEASE, __HIP_MEMORY_SCOPE_AGENT)
// SYSTEM scope: sc0+sc1 -> L3 coherence point (R4: == agent for relaxed ops).
#define LOADS(p)      __hip_atomic_load((p), __ATOMIC_RELAXED, __HIP_MEMORY_SCOPE_SYSTEM)
#define EXCHS(p, v)   (void)__hip_atomic_exchange((p), (v), __ATOMIC_RELAXED, __HIP_MEMORY_SCOPE_SYSTEM)

// sc0-only access: bypasses L1, served by the local XCD L2 (~250 cy) — the
// fast path when publisher+reader share an XCD. NOT globally coherent; always
// paired with a system-scope fallback for correctness (hybrid spin).
static __device__ __forceinline__ u64 ld_sc0(const u64* p) {
  u64 v;
  asm volatile("global_load_dwordx2 %0, %1, off sc0\n\ts_waitcnt vmcnt(0)"
               : "=v"(v) : "v"(p) : "memory");
  return v;
}
static __device__ __forceinline__ void st_sc0(u64* p, u64 v) {
  asm volatile("global_store_dwordx2 %0, %1, off sc0" :: "v"(p), "v"(v) : "memory");
}

// ============================================================================
// Kernel 1: GEMM (phase A) + fence + pool (phase B).  256 WGs x 256 threads.
// (byte-identical control)
// ============================================================================
__global__ __launch_bounds__(256, 1) void k_gemm_pool(
    const float* __restrict__ base_out, const float* __restrict__ dist,
    const float* __restrict__ w_a,
    float* __restrict__ part, float* __restrict__ pooled,
    unsigned* __restrict__ tagA)
{
  const int wg = blockIdx.x;   // 0..255
  const int tid = threadIdx.x; // 0..255

  __shared__ __align__(16) unsigned short Ah[16 * 40], Al[16 * 40];   // w_a tile hi/lo, pad-40 swizzle
  __shared__ __align__(16) unsigned short Bh[192 * 40], Bl[192 * 40]; // base_sel tile hi/lo
  __shared__ float Asum_s[KK * MM * MM];

  {
    const int ks = wg >> 6, ot = wg & 63;
    const int cc0 = ks * 1024;
    const int wave = tid >> 6, lane = tid & 63;
    const int jf0 = wave * 3;          // this wave's 3 j-fragments

    const int sq = tid & 7;            // cc float4 quad (0..7)
    const int sr = tid >> 3;           // staging row (0..31)
    unsigned boff[6];
#pragma unroll
    for (int rep = 0; rep < 6; ++rep) {
      const int j = sr + 32 * rep;     // 0..191
      const int n = j / 12, m = j - n * 12;
      boff[rep] = (unsigned)(((n * TT + 31) * MM + m) * CIN + cc0 + sq * 4);
    }
    const bool aact = tid < 128;       // A tile: 16 rows x 32cc = 128 float4
    unsigned aoff = aact ? (unsigned)((ot * 16 + (tid >> 3)) * CIN + cc0 + sq * 4) : 0u;

    f32x4 acc0 = {0.f, 0.f, 0.f, 0.f}, acc1 = acc0, acc2 = acc0;

    float4 pa, pb[6];
    if (aact) pa = *(const float4*)&w_a[aoff];
#pragma unroll
    for (int rep = 0; rep < 6; ++rep) pb[rep] = *(const float4*)&base_out[boff[rep]];

    for (int st = 0; st < 32; ++st) {
      __syncthreads();
      if (aact) {
        const int idx = (tid >> 3) * 40 + sq * 4;
        unsigned ux = __float_as_uint(pa.x), uy = __float_as_uint(pa.y);
        unsigned uz = __float_as_uint(pa.z), uw = __float_as_uint(pa.w);
        *(uint2*)&Ah[idx] = make_uint2((ux >> 16) | (uy & 0xFFFF0000u),
                                       (uz >> 16) | (uw & 0xFFFF0000u));
        unsigned lx = __float_as_uint(pa.x - __uint_as_float(ux & 0xFFFF0000u));
        unsigned ly = __float_as_uint(pa.y - __uint_as_float(uy & 0xFFFF0000u));
        unsigned lz = __float_as_uint(pa.z - __uint_as_float(uz & 0xFFFF0000u));
        unsigned lw = __float_as_uint(pa.w - __uint_as_float(uw & 0xFFFF0000u));
        *(uint2*)&Al[idx] = make_uint2((lx >> 16) | (ly & 0xFFFF0000u),
                                       (lz >> 16) | (lw & 0xFFFF0000u));
      }
#pragma unroll
      for (int rep = 0; rep < 6; ++rep) {
        const int idx = (sr + 32 * rep) * 40 + sq * 4;
        unsigned ux = __float_as_uint(pb[rep].x), uy = __float_as_uint(pb[rep].y);
        unsigned uz = __float_as_uint(pb[rep].z), uw = __float_as_uint(pb[rep].w);
        *(uint2*)&Bh[idx] = make_uint2((ux >> 16) | (uy & 0xFFFF0000u),
                                       (uz >> 16) | (uw & 0xFFFF0000u));
        unsigned lx = __float_as_uint(pb[rep].x - __uint_as_float(ux & 0xFFFF0000u));
        unsigned ly = __float_as_uint(pb[rep].y - __uint_as_float(uy & 0xFFFF0000u));
        unsigned lz = __float_as_uint(pb[rep].z - __uint_as_float(uz & 0xFFFF0000u));
        unsigned lw = __float_as_uint(pb[rep].w - __uint_as_float(uw & 0xFFFF0000u));
        *(uint2*)&Bl[idx] = make_uint2((lx >> 16) | (ly & 0xFFFF0000u),
                                       (lz >> 16) | (lw & 0xFFFF0000u));
      }
      __syncthreads();
      if (st < 31) {  // prefetch next 32cc under compute
        aoff += 32;
        if (aact) pa = *(const float4*)&w_a[aoff];
#pragma unroll
        for (int rep = 0; rep < 6; ++rep) {
          boff[rep] += 32;
          pb[rep] = *(const float4*)&base_out[boff[rep]];
        }
      }
      const int koff = (lane >> 4) * 8;
      const int fra = (lane & 15) * 40 + koff;
      bf16x8 oh = *(const bf16x8*)&Ah[fra];
      bf16x8 ol = *(const bf16x8*)&Al[fra];
      {
        const int r0 = ((jf0 + 0) * 16 + (lane & 15)) * 40 + koff;
        bf16x8 jh = *(const bf16x8*)&Bh[r0], jl = *(const bf16x8*)&Bl[r0];
        acc0 = MFMA_BF16(jh, oh, acc0);
        acc0 = MFMA_BF16(jh, ol, acc0);
        acc0 = MFMA_BF16(jl, oh, acc0);
      }
      {
        const int r1 = ((jf0 + 1) * 16 + (lane & 15)) * 40 + koff;
        bf16x8 jh = *(const bf16x8*)&Bh[r1], jl = *(const bf16x8*)&Bl[r1];
        acc1 = MFMA_BF16(jh, oh, acc1);
        acc1 = MFMA_BF16(jh, ol, acc1);
        acc1 = MFMA_BF16(jl, oh, acc1);
      }
      {
        const int r2 = ((jf0 + 2) * 16 + (lane & 15)) * 40 + koff;
        bf16x8 jh = *(const bf16x8*)&Bh[r2], jl = *(const bf16x8*)&Bl[r2];
        acc2 = MFMA_BF16(jh, oh, acc2);
        acc2 = MFMA_BF16(jh, ol, acc2);
        acc2 = MFMA_BF16(jl, oh, acc2);
      }
    }
    // C/D layout: col(o) = lane&15, row(j) = (lane>>4)*4 + reg   [m89-verified]
    const int o = ot * 16 + (lane & 15);
    const int jr = (lane >> 4) * 4;
#pragma unroll
    for (int r = 0; r < 4; ++r) {
      part[((size_t)ks * 192 + (jf0 + 0) * 16 + jr + r) * 1024 + o] = acc0[r];
      part[((size_t)ks * 192 + (jf0 + 1) * 16 + jr + r) * 1024 + o] = acc1[r];
      part[((size_t)ks * 192 + (jf0 + 2) * 16 + jr + r) * 1024 + o] = acc2[r];
    }
    __syncthreads();   // drains vmcnt -> all part stores in L2 before release
    if (tid == 0) STOREREL(&tagA[wg * 16], 1u);
  }

  // ---- fence: all GEMM tiles visible. Wave-0 sweep ----
  if (tid < 64) {
    bool done;
    do {
      unsigned a0 = LOADR(&tagA[(tid      ) * 16]);
      unsigned a1 = LOADR(&tagA[(tid +  64) * 16]);
      unsigned a2 = LOADR(&tagA[(tid + 128) * 16]);
      unsigned a3 = LOADR(&tagA[(tid + 192) * 16]);
      done = __all(a0 == 1u && a1 == 1u && a2 == 1u && a3 == 1u);
    } while (!done);
  }
  __syncthreads();
  (void)LOADACQ(&tagA[0]);   // orders subsequent plain loads of part

  // Phase B: pool — WG (n = wg>>4, c-block = (wg&15)*32)
  {
    const int n = wg >> 4, cb = (wg & 15) * 32;
    const unsigned dbase = (unsigned)((n * TT + 31) * (3 * KK * MM * MM));
    for (int f = tid; f < KK * MM * MM; f += 256)
      Asum_s[f] = dist[dbase + f] + dist[dbase + KK * MM * MM + f]
                + dist[dbase + 2 * KK * MM * MM + f];
    __syncthreads();
    if (tid < 32) {
      const int c = cb + tid;
      float nd[KK][MM];
#pragma unroll
      for (int k = 0; k < KK; ++k)
#pragma unroll
        for (int v = 0; v < MM; ++v) {
          const size_t off = (size_t)(n * MM + v) * 1024 + k * DD + c;
          nd[k][v] = part[off] + part[off + PART_KS_STRIDE]
                   + part[off + 2 * PART_KS_STRIDE] + part[off + 3 * PART_KS_STRIDE];
        }
      float accm = 0.f;
#pragma unroll
      for (int w = 0; w < MM; ++w) {
        float sw = 0.f;
#pragma unroll
        for (int k = 0; k < KK; ++k)
#pragma unroll
          for (int v = 0; v < MM; ++v) sw += nd[k][v] * Asum_s[(k * MM + v) * MM + w];
        accm += fmaxf(sw, 0.f);
      }
      pooled[n * DD + c] = accm * (1.f / 12.f);
    }
  }
  // pooled visibility to kernel 2 via the stream/kernel boundary.
}

// ============================================================================
// Kernel 2: 256 WGs x 1024 threads.
//  - WGs with (bid&7)!=0: gx producers (bid&7 in 1..4) or immediate exit.
//    gx handoff uses k1's proven release(tag)/relaxed-sweep pattern.
//  - WGs with (bid&7)==0: 32 LSTM workers -> with round-robin dispatch these
//    all land on XCD 0, making sc0 (L2-served) sync ~4x lower latency.
//    Correctness does NOT depend on placement: hybrid spin (sc0 / system
//    alternation) + durable system-scope atomic-exchange publish.
// ============================================================================
__global__ __launch_bounds__(1024, 1) void k_lstm(
    const float* __restrict__ pooled,
    const float* __restrict__ w_ih, const float* __restrict__ w_hh,
    const float* __restrict__ b_ih, const float* __restrict__ b_hh,
    const float* __restrict__ w_cls, const float* __restrict__ b_cls,
    unsigned* __restrict__ tagGX, float* __restrict__ gxg,
    u64* __restrict__ hg64, float* __restrict__ out)
{
  const int wg = blockIdx.x;    // 0..255
  const int tid = threadIdx.x;  // 0..1023

  __shared__ __align__(16) float whh_s[64][516];  // 132 KB; reused as h-history in classifier
  __shared__ float gx_s[16][64];                  // [step][local gate row]
  __shared__ __align__(16) float h_s[DD];
  __shared__ float dot_s[64];

  if ((wg & 7) != 0) {
    // ---- gx producer: gate rows gr = dd*16 + j, dd = m + 32*(k-1) ----
    const int k = wg & 7;
    if (k > 4) return;                 // 96 WGs exit immediately
    const int m = wg >> 3;             // 0..31 (serves worker w = m)
    const int dd = m + 32 * (k - 1);   // 0..127
    if (tid < 256) {
      const int n = tid & 15, j = tid >> 4;
      const int gr = dd * 16 + j;      // global gate row (g = k-1, dim = 16m+j)
      const float4* wr = (const float4*)&w_ih[(size_t)gr * DD];
      const float4* pv = (const float4*)&pooled[(size_t)n * DD];
      float a = 0.f;
#pragma unroll 8
      for (int q = 0; q < DD / 4; ++q) {
        float4 x = wr[q], y = pv[q];
        a += x.x * y.x + x.y * y.y + x.z * y.z + x.w * y.w;
      }
      // k2-native layout: gxg[w][n][rl], rl = (k-1)*16 + j
      gxg[m * 1024 + n * 64 + (k - 1) * 16 + j] = a + b_ih[gr] + b_hh[gr];
    }
    __syncthreads();   // drains vmcnt -> gx stores complete before release
    if (tid == 0) STOREREL(&tagGX[dd * 16], 1u);   // release: wbL2 -> L3
    return;
  }

  // ============================ LSTM worker =================================
  const int w = wg >> 3;   // 0..31; owns h-dims [w*16, w*16+16)

  // ---- stage whh rows (64 x 512 = 128 KB) ----
  for (int f = tid; f < 64 * 128; f += 1024) {
    const int rr = f >> 7, c4 = (f & 127) * 4;
    const int grow = (rr >> 4) * DD + w * 16 + (rr & 15);
    *(float4*)&whh_s[rr][c4] = *(const float4*)&w_hh[(size_t)grow * DD + c4];
  }
  // ---- wait for this worker's 4 gx tiles (k=1..4) ----
  if (tid < 64) {
    bool done;
    do {
      int t0 = (int)LOADR(&tagGX[(w + 32 * (tid & 3)) * 16]);
      done = __all(t0 == 1);           // 0xAA poison != 1
    } while (!done);
  }
  __syncthreads();
  // gx gather: system loads (bypass caches; producer released to L3)
  gx_s[tid >> 6][tid & 63] =
      __uint_as_float(LOADS((const unsigned*)&gxg[w * 1024 + tid]));
  __syncthreads();

  // ---- LSTM loop: 16 steps; hybrid sc0/system data-spin all-gather ----
  {
    float c_reg = 0.f;
    const int r = tid >> 4;    // local gate row 0..63
    const int lj = tid & 15;   // slice lane

    for (int s = 0; s < NV; ++s) {
      if (s == 0) {
        if (tid < DD) h_s[tid] = 0.f;
      } else {
        if (tid < DD) {
          const u64* p = &hg64[(size_t)(s - 1) * DD + tid];
          u64 v = ld_sc0(p);                       // fast path: local-XCD L2
          while ((unsigned)v != (unsigned)s) {
            v = LOADS(p);                          // fallback: L3 (guarantees progress)
            if ((unsigned)v == (unsigned)s) break;
            v = ld_sc0(p);
          }
          h_s[tid] = __uint_as_float((unsigned)(v >> 32));
        }
      }
      __syncthreads();

      float p = 0.f;
      const float4* wrow = (const float4*)&whh_s[r][0];
      const float4* hv4 = (const float4*)h_s;
#pragma unroll
      for (int q = 0; q < 8; ++q) {
        float4 wv = wrow[lj + 16 * q];
        float4 hv = hv4[lj + 16 * q];
        p += wv.x * hv.x + wv.y * hv.y + wv.z * hv.z + wv.w * hv.w;
      }
#pragma unroll
      for (int off = 8; off; off >>= 1) p += __shfl_down(p, off, 16);
      if (lj == 0) dot_s[r] = p;
      __syncthreads();

      if (tid < 16) {
        const float pi = gx_s[s][tid]      + dot_s[tid];
        const float pf = gx_s[s][16 + tid] + dot_s[16 + tid];
        const float pg = gx_s[s][32 + tid] + dot_s[32 + tid];
        const float po = gx_s[s][48 + tid] + dot_s[48 + tid];
        const float si = 1.f / (1.f + expf(-pi));
        const float sf = 1.f / (1.f + expf(-pf));
        const float so = 1.f / (1.f + expf(-po));
        c_reg = sf * c_reg + si * tanhf(pg);
        const float hn = so * tanhf(c_reg);
        const u64 pk = ((u64)__float_as_uint(hn) << 32) | (u64)(unsigned)(s + 1);
        u64* pp = &hg64[(size_t)s * DD + w * 16 + tid];
        st_sc0(pp, pk);    // fast visibility within this XCD's L2
        EXCHS(pp, pk);     // durable publish at the device coherence point
      }
      // h_s/dot_s only rewritten after next step's barriers (two barriers away)
    }
  }

  // ---- classifier tail (worker 0 = blockIdx 0) ----
  if (wg == 0) {
    float* scratch = &whh_s[0][0];   // rows stride 516 (whh dead now)
    if (tid < DD) {
      u64 vv[NV];
#pragma unroll
      for (int n = 0; n < NV; ++n) vv[n] = LOADS(&hg64[(size_t)n * DD + tid]);
#pragma unroll
      for (int n = 0; n < NV; ++n) {
        u64 v = vv[n];
        while ((unsigned)v != (unsigned)(n + 1))
          v = LOADS(&hg64[(size_t)n * DD + tid]);   // backstop
        scratch[n * 516 + tid] = __uint_as_float((unsigned)(v >> 32));
      }
    }
    __syncthreads();
    if (tid < NV * NCLS) {
      const int n = tid >> 3, cl = tid & 7;
      const float4* hv = (const float4*)&scratch[n * 516];
      const float4* wv = (const float4*)(w_cls + (size_t)cl * DD);
      float a = b_cls[cl];
#pragma unroll 8
      for (int q = 0; q < DD / 4; ++q) {
        float4 x = hv[q], y = wv[q];
        a += x.x * y.x + x.y * y.y + x.z * y.z + x.w * y.w;
      }
      out[tid] = a;
    }
  }
}

extern "C" void kernel_launch(void* const* d_in, const int* in_sizes, int n_in,
                              void* d_out, int out_size, void* d_ws, size_t ws_size,
                              hipStream_t stream) {
  const float* base_out = (const float*)d_in[0];
  const float* dist     = (const float*)d_in[1];
  const float* w_a      = (const float*)d_in[2];
  const float* w_ih     = (const float*)d_in[3];
  const float* w_hh     = (const float*)d_in[4];
  const float* b_ih     = (const float*)d_in[5];
  const float* b_hh     = (const float*)d_in[6];
  const float* w_cls    = (const float*)d_in[7];
  const float* b_cls    = (const float*)d_in[8];
  float* out = (float*)d_out;

  float* ws = (float*)d_ws;
  float* part   = ws + PART_F;
  float* pooled = ws + POOLED_F;
  unsigned* tagA  = (unsigned*)(ws + TAGA_F);
  unsigned* tagGX = (unsigned*)(ws + TAGGX_F);
  u64* hg64 = (u64*)(ws + HGLOB_F);
  float* gxg = ws + GX_F;

  // Tags/values self-validate against the 0xAA re-poison (poison low word
  // 0xAAAAAAAA never equals a live tag 1..16 / 1).
  // Kernel boundary on the stream provides part/pooled visibility to k_lstm.
  k_gemm_pool<<<dim3(256), 256, 0, stream>>>(base_out, dist, w_a, part, pooled, tagA);
  k_lstm<<<dim3(256), 1024, 0, stream>>>(pooled, w_ih, w_hh, b_ih, b_hh,
                                         w_cls, b_cls, tagGX, gxg, hg64, out);
}